// Round 3
// baseline (1681.536 us; speedup 1.0000x reference)
//
#include <hip/hip_runtime.h>
#include <hip/hip_bf16.h>

#define TT 6
#define NN 50000
#define EE 800000
#define FF 32
#define HH 64
#define OO 16

typedef __hip_bfloat16 bf16;
__device__ __forceinline__ float b2f(bf16 v){ return __bfloat162float(v); }

// dtype-flexible load: element i of p, as f32 if f32flag else bf16
__device__ __forceinline__ float ldf(const void* p, long long i, int f32){
  return f32 ? ((const float*)p)[i] : b2f(((const bf16*)p)[i]);
}

// fused weight buffer layout (float offsets)
#define OFF_M 0        // M[g][32][64], g = z,r,h : W_g @ L_g[:64]
#define OFF_B 6144     // B[g][64][64]            : L_g[64:]
#define OFF_C 18432    // c[g][64]                : b_g @ L_g[:64] + L_g_b
#define OFF_OW 18624   // out_W [64][16]
#define OFF_OB 19648   // out_b [16]
#define WBUF_N 19664

// ---------------- input-dtype detection ----------------
// Read xs as f32: true f32 N(0,1) values are ~all in |v|<100; bf16 pairs
// misread as f32 have exponent fields made of mantissa bits -> |v|~2^123.
__global__ void detect_kernel(const void* xs, int* __restrict__ flag){
  __shared__ int tot;
  if (threadIdx.x == 0) tot = 0;
  __syncthreads();
  const float* xf = (const float*)xs;   // 16 KB read, in-bounds for either dtype
  int cnt = 0;
  for (int i = threadIdx.x; i < 4096; i += 256){
    float a = fabsf(xf[i]);
    if (a < 100.f) cnt++;               // NaN compares false
  }
  atomicAdd(&tot, cnt);
  __syncthreads();
  if (threadIdx.x == 0) flag[0] = (tot >= 3500) ? 1 : 0;
}

// ---------------- zero ----------------
__global__ void zero_kernel(uint4* __restrict__ p, int n4){
  int i = blockIdx.x*256 + threadIdx.x;
  if (i < n4) p[i] = make_uint4(0,0,0,0);
}

// ---------------- fused-weight prep ----------------
__global__ void prep_kernel(const void* Wz,const void* bz,const void* Wr,const void* br,
                            const void* Wh,const void* bh,
                            const void* Lz,const void* Lzb,const void* Lr,const void* Lrb,
                            const void* Lh,const void* Lhb,
                            const void* oW,const void* ob,
                            const int* __restrict__ flag, float* __restrict__ wbuf){
  int f32 = flag[0];
  int idx = blockIdx.x*256 + threadIdx.x;
  if (idx >= WBUF_N) return;
  if (idx < OFF_B){                       // M[g][k][j] = sum_m W[k][m] * L[m][j]
    int g = idx >> 11; int r = idx & 2047; int k = r >> 6; int j = r & 63;
    const void* W = (g==0)?Wz:((g==1)?Wr:Wh);
    const void* L = (g==0)?Lz:((g==1)?Lr:Lh);
    float s = 0.f;
    for (int m=0;m<64;m++) s += ldf(W,k*64+m,f32) * ldf(L,m*64+j,f32);
    wbuf[idx] = s;
  } else if (idx < OFF_C){                // B[g][k][j] = L[(64+k)][j]
    int i = idx - OFF_B; int g = i >> 12; int r = i & 4095; int k = r >> 6; int j = r & 63;
    const void* L = (g==0)?Lz:((g==1)?Lr:Lh);
    wbuf[idx] = ldf(L,(64+k)*64 + j,f32);
  } else if (idx < OFF_OW){               // c[g][j] = sum_m b[m]*L[m][j] + Lb[j]
    int i = idx - OFF_C; int g = i >> 6; int j = i & 63;
    const void* L  = (g==0)?Lz:((g==1)?Lr:Lh);
    const void* bb = (g==0)?bz:((g==1)?br:bh);
    const void* Lb = (g==0)?Lzb:((g==1)?Lrb:Lhb);
    float s = ldf(Lb,j,f32);
    for (int m=0;m<64;m++) s += ldf(bb,m,f32) * ldf(L,m*64+j,f32);
    wbuf[idx] = s;
  } else if (idx < OFF_OB){
    wbuf[idx] = ldf(oW,idx - OFF_OW,f32);
  } else {
    wbuf[idx] = ldf(ob,idx - OFF_OB,f32);
  }
}

// ---------------- CSR build ----------------
__global__ void count_kernel(const int* __restrict__ ei, int* __restrict__ deg){
  int t = blockIdx.y;
  int e = blockIdx.x*256 + threadIdx.x;
  int d = ei[t*2*EE + EE + e];
  atomicAdd(&deg[t*NN + d], 1);
}

__global__ __launch_bounds__(1024) void scan_kernel(const int* __restrict__ deg,
                                                    int* __restrict__ rowstart,
                                                    int* __restrict__ cursor){
  int t = blockIdx.x;
  const int* d = deg + t*NN;
  int* rsp = rowstart + t*(NN+1);
  int* cur = cursor + t*NN;
  __shared__ int wsum[16];
  __shared__ int carry_s;
  if (threadIdx.x == 0) carry_s = 0;
  __syncthreads();
  int lane = threadIdx.x & 63;
  int wid  = threadIdx.x >> 6;
  for (int base = 0; base < NN; base += 1024){
    int i = base + threadIdx.x;
    int v = (i < NN) ? d[i] : 0;
    int x = v;
    #pragma unroll
    for (int off = 1; off < 64; off <<= 1){
      int y = __shfl_up(x, off, 64);
      if (lane >= off) x += y;
    }
    if (lane == 63) wsum[wid] = x;
    __syncthreads();
    if (threadIdx.x == 0){
      int s = 0;
      #pragma unroll
      for (int ww = 0; ww < 16; ww++){ int tmp = wsum[ww]; wsum[ww] = s; s += tmp; }
    }
    __syncthreads();
    int excl = x - v + wsum[wid] + carry_s;
    if (i < NN){ rsp[i] = excl; cur[i] = excl; }
    __syncthreads();                       // all reads of carry_s done
    if (threadIdx.x == 1023) carry_s = excl + v;
    __syncthreads();
  }
  if (threadIdx.x == 0) rsp[NN] = carry_s;
}

__global__ void fill_kernel(const int* __restrict__ ei, int* __restrict__ cursor,
                            int* __restrict__ csr){
  int t = blockIdx.y;
  int e = blockIdx.x*256 + threadIdx.x;
  int s = ei[t*2*EE + e];
  int d = ei[t*2*EE + EE + e];
  int pos = atomicAdd(&cursor[t*NN + d], 1);
  csr[t*EE + pos] = s;
}

__global__ void dinv_kernel(const int* __restrict__ deg, float* __restrict__ dnv){
  int i = blockIdx.x*256 + threadIdx.x;
  if (i < TT*NN) dnv[i] = rsqrtf((float)(deg[i] + 1));   // +1 self loop
}

// ---------------- aggregation for one t:
// agg[n][f] = dinv[n]*( dinv[n]*x[n][f] + sum_s dinv[s]*x[s][f] )
__global__ __launch_bounds__(256) void gather_kernel(int t, const void* xs,
                                                     const float* __restrict__ dinv,
                                                     const int* __restrict__ rowstart,
                                                     const int* __restrict__ csr,
                                                     const int* __restrict__ flag,
                                                     float* __restrict__ agg){
  int n = blockIdx.x*8 + (threadIdx.x >> 5);
  int f = threadIdx.x & 31;
  if (n >= NN) return;
  int f32 = flag[0];
  const float* dv = dinv + t*NN;
  long long xbase = (long long)t*NN*FF;
  float dn = dv[n];
  int b0 = rowstart[t*(NN+1) + n];
  int b1 = rowstart[t*(NN+1) + n + 1];
  const int* cs = csr + t*EE;
  float acc;
  if (f32){
    const float* xt = (const float*)xs + xbase;
    acc = dn * xt[n*FF + f];
    for (int i = b0; i < b1; i++){
      int s = cs[i];
      acc += dv[s] * xt[s*FF + f];
    }
  } else {
    const bf16* xt = (const bf16*)xs + xbase;
    acc = dn * b2f(xt[n*FF + f]);
    for (int i = b0; i < b1; i++){
      int s = cs[i];
      acc += dv[s] * b2f(xt[s*FF + f]);
    }
  }
  agg[(long long)n*FF + f] = acc * dn;
}

// ---------------- fused GRU step: R, Z, Htilde, h update (node-local) ----------------
__global__ __launch_bounds__(256) void gate_kernel(const float* __restrict__ aggt,
                                                   float* __restrict__ h,
                                                   const float* __restrict__ w){
  __shared__ float As[64][33];
  __shared__ float Hs[64][65];
  __shared__ float HRs[64][65];
  int tid = threadIdx.x;
  int nb = blockIdx.x*64;
  #pragma unroll
  for (int r = 0; r < 8; r++){
    int i = tid + 256*r; int n = i >> 5, k = i & 31; int gn = nb + n;
    As[n][k] = (gn < NN) ? aggt[gn*FF + k] : 0.f;
  }
  #pragma unroll
  for (int r = 0; r < 16; r++){
    int i = tid + 256*r; int n = i >> 6, k = i & 63; int gn = nb + n;
    Hs[n][k] = (gn < NN) ? h[gn*HH + k] : 0.f;
  }
  __syncthreads();
  int node = tid & 63;
  int j0 = __builtin_amdgcn_readfirstlane((tid >> 6) * 16);  // wave-uniform

  // ---- R = sigmoid(agg@Mr + h@Br + cr); stage h*R to LDS ----
  float acc[16];
  #pragma unroll
  for (int jj = 0; jj < 16; jj++) acc[jj] = w[OFF_C + 64 + j0 + jj];
  #pragma unroll
  for (int k = 0; k < 32; k++){
    float a = As[node][k];
    const float* wr = w + OFF_M + 2048 + k*64 + j0;
    #pragma unroll
    for (int jj = 0; jj < 16; jj++) acc[jj] += a * wr[jj];
  }
  #pragma unroll
  for (int k = 0; k < 64; k++){
    float a = Hs[node][k];
    const float* wr = w + OFF_B + 4096 + k*64 + j0;
    #pragma unroll
    for (int jj = 0; jj < 16; jj++) acc[jj] += a * wr[jj];
  }
  #pragma unroll
  for (int jj = 0; jj < 16; jj++){
    float rr = 1.f / (1.f + __expf(-acc[jj]));
    HRs[node][j0 + jj] = Hs[node][j0 + jj] * rr;
  }
  __syncthreads();

  // ---- Z and Htilde together ----
  float az[16], ah[16];
  #pragma unroll
  for (int jj = 0; jj < 16; jj++){
    az[jj] = w[OFF_C + j0 + jj];
    ah[jj] = w[OFF_C + 128 + j0 + jj];
  }
  #pragma unroll
  for (int k = 0; k < 32; k++){
    float a = As[node][k];
    const float* wz = w + OFF_M + k*64 + j0;
    const float* wh = w + OFF_M + 4096 + k*64 + j0;
    #pragma unroll
    for (int jj = 0; jj < 16; jj++){ az[jj] += a*wz[jj]; ah[jj] += a*wh[jj]; }
  }
  #pragma unroll
  for (int k = 0; k < 64; k++){
    float hk  = Hs[node][k];
    float hrk = HRs[node][k];
    const float* wz = w + OFF_B + k*64 + j0;
    const float* wh = w + OFF_B + 8192 + k*64 + j0;
    #pragma unroll
    for (int jj = 0; jj < 16; jj++){ az[jj] += hk*wz[jj]; ah[jj] += hrk*wh[jj]; }
  }
  float hnew[16];
  #pragma unroll
  for (int jj = 0; jj < 16; jj++){
    float z = 1.f / (1.f + __expf(-az[jj]));
    float x = ah[jj];
    float e = __expf(-2.f * fabsf(x));
    float th = (1.f - e) / (1.f + e);
    th = (x < 0.f) ? -th : th;
    hnew[jj] = z * Hs[node][j0 + jj] + (1.f - z) * th;
  }
  __syncthreads();                          // all HRs reads done
  #pragma unroll
  for (int jj = 0; jj < 16; jj++) HRs[node][j0 + jj] = hnew[jj];
  __syncthreads();
  #pragma unroll
  for (int r = 0; r < 16; r++){
    int i = tid + 256*r; int n = i >> 6, k = i & 63; int gn = nb + n;
    if (gn < NN) h[gn*HH + k] = HRs[n][k];
  }
}

// ---------------- final projection h @ out_W + out_b -> f32 ----------------
__global__ __launch_bounds__(256) void out_kernel(const float* __restrict__ h,
                                                  const float* __restrict__ w,
                                                  float* __restrict__ out){
  __shared__ float Hl[16][65];
  __shared__ float Wl[64][16];
  __shared__ float bl[16];
  int tid = threadIdx.x;
  int nb = blockIdx.x*16;
  #pragma unroll
  for (int r = 0; r < 4; r++){
    int i = tid + 256*r;
    int n = i >> 6, k = i & 63; int gn = nb + n;
    Hl[n][k] = (gn < NN) ? h[gn*HH + k] : 0.f;
    Wl[(i >> 4) & 63][i & 15] = w[OFF_OW + i];
  }
  if (tid < 16) bl[tid] = w[OFF_OB + tid];
  __syncthreads();
  int n = tid >> 4; int o = tid & 15;
  float acc = bl[o];
  #pragma unroll
  for (int k = 0; k < 64; k++) acc += Hl[n][k] * Wl[k][o];
  int gn = nb + n;
  if (gn < NN) out[gn*OO + o] = acc;
}

extern "C" void kernel_launch(void* const* d_in, const int* in_sizes, int n_in,
                              void* d_out, int out_size, void* d_ws, size_t ws_size,
                              hipStream_t stream) {
  const void* xs = d_in[0];
  const int*  ei = (const int*)d_in[1];
  float* out = (float*)d_out;
  char* ws = (char*)d_ws;
  // workspace layout (bytes); total ~43.3 MB
  float* h    = (float*)(ws + 0);          // 50000*64*4   = 12,800,000
  float* agg  = (float*)(ws + 12800000);   // 50000*32*4   =  6,400,000 (per-t reuse)
  int*   deg  = (int*)  (ws + 19200000);   // 6*50000*4    =  1,200,000
  int*   rs   = (int*)  (ws + 20400000);   // 6*50001*4    =  1,200,024
  int*   cur  = (int*)  (ws + 21600128);   // 6*50000*4
  float* dnv  = (float*)(ws + 22800128);   // 6*50000*4
  int*   csr  = (int*)  (ws + 24000128);   // 6*800000*4   = 19,200,000
  float* wbuf = (float*)(ws + 43200128);   // 19664*4      = 78,656
  int*   flag = (int*)  (ws + 43278784);   // 4

  detect_kernel<<<1, 256, 0, stream>>>(xs, flag);
  prep_kernel<<<(WBUF_N + 255)/256, 256, 0, stream>>>(d_in[2],d_in[3],d_in[4],d_in[5],
      d_in[6],d_in[7],d_in[8],d_in[9],d_in[10],d_in[11],d_in[12],d_in[13],d_in[14],d_in[15],
      flag, wbuf);
  zero_kernel<<<(800000 + 255)/256, 256, 0, stream>>>((uint4*)(ws + 0), 800000);       // h
  zero_kernel<<<(75000 + 255)/256, 256, 0, stream>>>((uint4*)(ws + 19200000), 75000);  // deg
  count_kernel<<<dim3(EE/256, TT), 256, 0, stream>>>(ei, deg);
  scan_kernel<<<TT, 1024, 0, stream>>>(deg, rs, cur);
  fill_kernel<<<dim3(EE/256, TT), 256, 0, stream>>>(ei, cur, csr);
  dinv_kernel<<<(TT*NN + 255)/256, 256, 0, stream>>>(deg, dnv);
  for (int t = 0; t < TT; t++){
    gather_kernel<<<dim3((NN + 7)/8), 256, 0, stream>>>(t, xs, dnv, rs, csr, flag, agg);
    gate_kernel<<<(NN + 63)/64, 256, 0, stream>>>(agg, h, wbuf);
  }
  out_kernel<<<NN/16, 256, 0, stream>>>(h, wbuf, out);
}

// Round 4
// 1463.421 us; speedup vs baseline: 1.1490x; 1.1490x over previous
//
#include <hip/hip_runtime.h>
#include <hip/hip_bf16.h>

#define TT 6
#define NN 50000
#define EE 800000
#define FF 32
#define HH 64
#define OO 16

#define NB 256        // dst buckets
#define DPB 196       // dsts per bucket (256*196 = 50176 >= 50000)
#define CHUNK 4096    // edges per block in hist/scatter

// fused weight buffer layout (float offsets)
#define OFF_M 0        // M[g][32][64], g = z,r,h : W_g @ L_g[:64]
#define OFF_B 6144     // B[g][64][64]            : L_g[64:]
#define OFF_C 18432    // c[g][64]                : b_g @ L_g[:64] + L_g_b
#define OFF_OW 18624   // out_W [64][16]
#define OFF_OB 19648   // out_b [16]
#define WBUF_N 19664

__device__ __forceinline__ float ldf(const void* p, int i){ return ((const float*)p)[i]; }

// ---------------- zero ----------------
__global__ void zero_kernel(uint4* __restrict__ p, int n4){
  int i = blockIdx.x*256 + threadIdx.x;
  if (i < n4) p[i] = make_uint4(0,0,0,0);
}

// ---------------- fused-weight prep (all inputs f32) ----------------
__global__ void prep_kernel(const void* Wz,const void* bz,const void* Wr,const void* br,
                            const void* Wh,const void* bh,
                            const void* Lz,const void* Lzb,const void* Lr,const void* Lrb,
                            const void* Lh,const void* Lhb,
                            const void* oW,const void* ob, float* __restrict__ wbuf){
  int idx = blockIdx.x*256 + threadIdx.x;
  if (idx >= WBUF_N) return;
  if (idx < OFF_B){                       // M[g][k][j] = sum_m W[k][m] * L[m][j]
    int g = idx >> 11; int r = idx & 2047; int k = r >> 6; int j = r & 63;
    const void* W = (g==0)?Wz:((g==1)?Wr:Wh);
    const void* L = (g==0)?Lz:((g==1)?Lr:Lh);
    float s = 0.f;
    for (int m=0;m<64;m++) s += ldf(W,k*64+m) * ldf(L,m*64+j);
    wbuf[idx] = s;
  } else if (idx < OFF_C){                // B[g][k][j] = L[(64+k)][j]
    int i = idx - OFF_B; int g = i >> 12; int r = i & 4095; int k = r >> 6; int j = r & 63;
    const void* L = (g==0)?Lz:((g==1)?Lr:Lh);
    wbuf[idx] = ldf(L,(64+k)*64 + j);
  } else if (idx < OFF_OW){               // c[g][j] = sum_m b[m]*L[m][j] + Lb[j]
    int i = idx - OFF_C; int g = i >> 6; int j = i & 63;
    const void* L  = (g==0)?Lz:((g==1)?Lr:Lh);
    const void* bb = (g==0)?bz:((g==1)?br:bh);
    const void* Lb = (g==0)?Lzb:((g==1)?Lrb:Lhb);
    float s = ldf(Lb,j);
    for (int m=0;m<64;m++) s += ldf(bb,m) * ldf(L,m*64+j);
    wbuf[idx] = s;
  } else if (idx < OFF_OB){
    wbuf[idx] = ldf(oW,idx - OFF_OW);
  } else {
    wbuf[idx] = ldf(ob,idx - OFF_OB);
  }
}

// ---------------- pass 1: per-t bucket histogram ----------------
__global__ __launch_bounds__(256) void hist_kernel(const int* __restrict__ ei,
                                                   int* __restrict__ bcnt){
  int t = blockIdx.y;
  __shared__ int cnt[NB];
  int tid = threadIdx.x;
  cnt[tid] = 0;
  __syncthreads();
  int e0 = blockIdx.x*CHUNK;
  const int* dsts = ei + t*2*EE + EE;
  #pragma unroll
  for (int i = 0; i < CHUNK/256; i++){
    int e = e0 + i*256 + tid;
    if (e < EE) atomicAdd(&cnt[dsts[e]/DPB], 1);
  }
  __syncthreads();
  if (cnt[tid] > 0) atomicAdd(&bcnt[t*NB + tid], cnt[tid]);
}

// ---------------- pass 2: scan bucket counts -> starts & cursors ----------------
__global__ __launch_bounds__(256) void bscan_kernel(const int* __restrict__ bcnt,
                                                    int* __restrict__ bstart,
                                                    int* __restrict__ bcur){
  int t = blockIdx.x;
  int tid = threadIdx.x;
  int v = bcnt[t*NB + tid];
  int lane = tid & 63, wid = tid >> 6;
  int x = v;
  #pragma unroll
  for (int off = 1; off < 64; off <<= 1){
    int y = __shfl_up(x, off, 64);
    if (lane >= off) x += y;
  }
  __shared__ int wsum[4];
  if (lane == 63) wsum[wid] = x;
  __syncthreads();
  if (tid == 0){
    int s = 0;
    #pragma unroll
    for (int w = 0; w < 4; w++){ int tmp = wsum[w]; wsum[w] = s; s += tmp; }
  }
  __syncthreads();
  int excl = x - v + wsum[wid];
  bstart[t*(NB+1) + tid] = excl;
  bcur[t*NB + tid] = excl;
  if (tid == NB-1) bstart[t*(NB+1) + NB] = excl + v;   // == EE
}

// ---------------- pass 3: block-aggregated scatter into bucket runs ----------------
// packed entry: (dstlo << 16) | src   (src < 50000 < 2^16, dstlo < 196)
__global__ __launch_bounds__(256) void scatter_kernel(const int* __restrict__ ei,
                                                      int* __restrict__ bcur,
                                                      unsigned int* __restrict__ csrp){
  int t = blockIdx.y;
  __shared__ int cnt[NB];
  __shared__ int base[NB];
  int tid = threadIdx.x;
  cnt[tid] = 0;
  __syncthreads();
  int e0 = blockIdx.x*CHUNK;
  const int* srcs = ei + t*2*EE;
  const int* dsts = ei + t*2*EE + EE;
  int pk[CHUNK/256];        // (b<<12) | local_rank
  unsigned int pay[CHUNK/256];
  #pragma unroll
  for (int i = 0; i < CHUNK/256; i++){
    int e = e0 + i*256 + tid;
    if (e < EE){
      int s = srcs[e], d = dsts[e];
      int b = d / DPB;
      int lr = atomicAdd(&cnt[b], 1);
      pk[i] = (b << 12) | lr;
      pay[i] = ((unsigned)(d - b*DPB) << 16) | (unsigned)s;
    } else pk[i] = -1;
  }
  __syncthreads();
  if (cnt[tid] > 0) base[tid] = atomicAdd(&bcur[t*NB + tid], cnt[tid]);
  __syncthreads();
  unsigned int* cp = csrp + (size_t)t*EE;
  #pragma unroll
  for (int i = 0; i < CHUNK/256; i++){
    if (pk[i] >= 0){
      int b = pk[i] >> 12, lr = pk[i] & 4095;
      cp[base[b] + lr] = pay[i];
    }
  }
}

// ---------------- pass 4: per-bucket degree -> dinv ----------------
__global__ __launch_bounds__(256) void degdinv_kernel(const unsigned int* __restrict__ csrp,
                                                      const int* __restrict__ bstart,
                                                      float* __restrict__ dinv){
  int b = blockIdx.x, t = blockIdx.y, tid = threadIdx.x;
  __shared__ int cnt[DPB];
  for (int i = tid; i < DPB; i += 256) cnt[i] = 0;
  __syncthreads();
  int b0 = bstart[t*(NB+1) + b], b1 = bstart[t*(NB+1) + b + 1];
  const unsigned int* cp = csrp + (size_t)t*EE;
  for (int i = b0 + tid; i < b1; i += 256)
    atomicAdd(&cnt[cp[i] >> 16], 1);
  __syncthreads();
  for (int i = tid; i < DPB; i += 256){
    int n = b*DPB + i;
    if (n < NN) dinv[t*NN + n] = rsqrtf((float)(cnt[i] + 1));  // +1 self loop
  }
}

// ---------------- pass 5: bucket-fused gather (all t in one dispatch) ----------
// agg[t][n][f] = dinv[n]*( dinv[n]*x[n][f] + sum_s dinv[s]*x[s][f] )
__global__ __launch_bounds__(256) void gatherb_kernel(const float* __restrict__ xs,
                                                      const float* __restrict__ dinv,
                                                      const unsigned int* __restrict__ csrp,
                                                      const int* __restrict__ bstart,
                                                      float* __restrict__ agg){
  int b = blockIdx.x, t = blockIdx.y, tid = threadIdx.x;
  __shared__ float acc[DPB][FF];          // 25,088 B
  for (int i = tid; i < DPB*FF; i += 256) ((float*)acc)[i] = 0.f;
  __syncthreads();
  int b0 = bstart[t*(NB+1) + b], b1 = bstart[t*(NB+1) + b + 1];
  const float* xt = xs + (size_t)t*NN*FF;
  const float* dv = dinv + t*NN;
  const unsigned int* cp = csrp + (size_t)t*EE;
  int f = tid & 31;
  for (int idx = b0 + (tid >> 5); idx < b1; idx += 8){
    unsigned int p = cp[idx];
    int s = p & 0xFFFFu;
    int dlo = p >> 16;
    float v = dv[s] * xt[(size_t)s*FF + f];
    atomicAdd(&acc[dlo][f], v);
  }
  __syncthreads();
  int dstbase = b*DPB;
  for (int i = tid >> 5; i < DPB; i += 8){
    int n = dstbase + i;
    if (n < NN){
      float dn = dv[n];
      agg[((size_t)t*NN + n)*FF + f] = dn*(acc[i][f] + dn*xt[(size_t)n*FF + f]);
    }
  }
}

// ---------------- fused GRU step: R, Z, Htilde, h update (node-local) ----------------
__global__ __launch_bounds__(256) void gate_kernel(const float* __restrict__ aggt,
                                                   float* __restrict__ h,
                                                   const float* __restrict__ w){
  __shared__ float As[64][33];
  __shared__ float Hs[64][65];
  __shared__ float HRs[64][65];
  int tid = threadIdx.x;
  int nb = blockIdx.x*64;
  #pragma unroll
  for (int r = 0; r < 8; r++){
    int i = tid + 256*r; int n = i >> 5, k = i & 31; int gn = nb + n;
    As[n][k] = (gn < NN) ? aggt[gn*FF + k] : 0.f;
  }
  #pragma unroll
  for (int r = 0; r < 16; r++){
    int i = tid + 256*r; int n = i >> 6, k = i & 63; int gn = nb + n;
    Hs[n][k] = (gn < NN) ? h[gn*HH + k] : 0.f;
  }
  __syncthreads();
  int node = tid & 63;
  int j0 = __builtin_amdgcn_readfirstlane((tid >> 6) * 16);  // wave-uniform

  // ---- R = sigmoid(agg@Mr + h@Br + cr); stage h*R to LDS ----
  float acc[16];
  #pragma unroll
  for (int jj = 0; jj < 16; jj++) acc[jj] = w[OFF_C + 64 + j0 + jj];
  #pragma unroll
  for (int k = 0; k < 32; k++){
    float a = As[node][k];
    const float* wr = w + OFF_M + 2048 + k*64 + j0;
    #pragma unroll
    for (int jj = 0; jj < 16; jj++) acc[jj] += a * wr[jj];
  }
  #pragma unroll
  for (int k = 0; k < 64; k++){
    float a = Hs[node][k];
    const float* wr = w + OFF_B + 4096 + k*64 + j0;
    #pragma unroll
    for (int jj = 0; jj < 16; jj++) acc[jj] += a * wr[jj];
  }
  #pragma unroll
  for (int jj = 0; jj < 16; jj++){
    float rr = 1.f / (1.f + __expf(-acc[jj]));
    HRs[node][j0 + jj] = Hs[node][j0 + jj] * rr;
  }
  __syncthreads();

  // ---- Z and Htilde together ----
  float az[16], ah[16];
  #pragma unroll
  for (int jj = 0; jj < 16; jj++){
    az[jj] = w[OFF_C + j0 + jj];
    ah[jj] = w[OFF_C + 128 + j0 + jj];
  }
  #pragma unroll
  for (int k = 0; k < 32; k++){
    float a = As[node][k];
    const float* wz = w + OFF_M + k*64 + j0;
    const float* wh = w + OFF_M + 4096 + k*64 + j0;
    #pragma unroll
    for (int jj = 0; jj < 16; jj++){ az[jj] += a*wz[jj]; ah[jj] += a*wh[jj]; }
  }
  #pragma unroll
  for (int k = 0; k < 64; k++){
    float hk  = Hs[node][k];
    float hrk = HRs[node][k];
    const float* wz = w + OFF_B + k*64 + j0;
    const float* wh = w + OFF_B + 8192 + k*64 + j0;
    #pragma unroll
    for (int jj = 0; jj < 16; jj++){ az[jj] += hk*wz[jj]; ah[jj] += hrk*wh[jj]; }
  }
  float hnew[16];
  #pragma unroll
  for (int jj = 0; jj < 16; jj++){
    float z = 1.f / (1.f + __expf(-az[jj]));
    float x = ah[jj];
    float e = __expf(-2.f * fabsf(x));
    float th = (1.f - e) / (1.f + e);
    th = (x < 0.f) ? -th : th;
    hnew[jj] = z * Hs[node][j0 + jj] + (1.f - z) * th;
  }
  __syncthreads();                          // all HRs reads done
  #pragma unroll
  for (int jj = 0; jj < 16; jj++) HRs[node][j0 + jj] = hnew[jj];
  __syncthreads();
  #pragma unroll
  for (int r = 0; r < 16; r++){
    int i = tid + 256*r; int n = i >> 6, k = i & 63; int gn = nb + n;
    if (gn < NN) h[gn*HH + k] = HRs[n][k];
  }
}

// ---------------- final projection h @ out_W + out_b -> f32 ----------------
__global__ __launch_bounds__(256) void out_kernel(const float* __restrict__ h,
                                                  const float* __restrict__ w,
                                                  float* __restrict__ out){
  __shared__ float Hl[16][65];
  __shared__ float Wl[64][16];
  __shared__ float bl[16];
  int tid = threadIdx.x;
  int nb = blockIdx.x*16;
  #pragma unroll
  for (int r = 0; r < 4; r++){
    int i = tid + 256*r;
    int n = i >> 6, k = i & 63; int gn = nb + n;
    Hl[n][k] = (gn < NN) ? h[gn*HH + k] : 0.f;
    Wl[(i >> 4) & 63][i & 15] = w[OFF_OW + i];
  }
  if (tid < 16) bl[tid] = w[OFF_OB + tid];
  __syncthreads();
  int n = tid >> 4; int o = tid & 15;
  float acc = bl[o];
  #pragma unroll
  for (int k = 0; k < 64; k++) acc += Hl[n][k] * Wl[k][o];
  int gn = nb + n;
  if (gn < NN) out[gn*OO + o] = acc;
}

extern "C" void kernel_launch(void* const* d_in, const int* in_sizes, int n_in,
                              void* d_out, int out_size, void* d_ws, size_t ws_size,
                              hipStream_t stream) {
  const float* xs = (const float*)d_in[0];
  const int*   ei = (const int*)d_in[1];
  float* out = (float*)d_out;
  char* ws = (char*)d_ws;
  // workspace layout (bytes); total ~71.7 MB
  float*        h      = (float*)(ws + 0);           // 12,800,000
  float*        agg    = (float*)(ws + 12800000);    // 38,400,000
  unsigned int* csrp   = (unsigned int*)(ws + 51200000); // 19,200,000
  float*        dinv   = (float*)(ws + 70400000);    // 1,200,000
  int*          bcnt   = (int*)  (ws + 71600000);    // 6*256*4 = 6144
  int*          bstart = (int*)  (ws + 71608000);    // 6*257*4 = 6168
  int*          bcur   = (int*)  (ws + 71616000);    // 6144
  float*        wbuf   = (float*)(ws + 71624000);    // 78,656 -> end 71,702,656

  // zero h (800000 uint4) and bcnt (384 uint4)
  zero_kernel<<<(800000 + 255)/256, 256, 0, stream>>>((uint4*)(ws + 0), 800000);
  zero_kernel<<<2, 256, 0, stream>>>((uint4*)(ws + 71600000), 384);
  prep_kernel<<<(WBUF_N + 255)/256, 256, 0, stream>>>(d_in[2],d_in[3],d_in[4],d_in[5],
      d_in[6],d_in[7],d_in[8],d_in[9],d_in[10],d_in[11],d_in[12],d_in[13],d_in[14],d_in[15],
      wbuf);
  hist_kernel<<<dim3((EE + CHUNK-1)/CHUNK, TT), 256, 0, stream>>>(ei, bcnt);
  bscan_kernel<<<TT, 256, 0, stream>>>(bcnt, bstart, bcur);
  scatter_kernel<<<dim3((EE + CHUNK-1)/CHUNK, TT), 256, 0, stream>>>(ei, bcur, csrp);
  degdinv_kernel<<<dim3(NB, TT), 256, 0, stream>>>(csrp, bstart, dinv);
  gatherb_kernel<<<dim3(NB, TT), 256, 0, stream>>>(xs, dinv, csrp, bstart, agg);
  for (int t = 0; t < TT; t++)
    gate_kernel<<<(NN + 63)/64, 256, 0, stream>>>(agg + (size_t)t*NN*FF, h, wbuf);
  out_kernel<<<NN/16, 256, 0, stream>>>(h, wbuf, out);
}